// Round 19
// baseline (41.459 us; speedup 1.0000x reference)
//
#include <hip/hip_runtime.h>

#define T_LEN 4096
#define H 16
#define N 16
#define D 64
#define NC 256
#define CL (T_LEN / NC)   // 16
#define CPB 4             // chunks (waves) per block -> 256-thread blocks
#define HND (H * N * D)   // 16384

static __device__ __forceinline__ unsigned short f2bf(float f) {
    union { float f; unsigned u; } v; v.f = f;
    unsigned r = (v.u + 0x7fffu + ((v.u >> 16) & 1u)) >> 16;
    return (unsigned short)r;
}
static __device__ __forceinline__ float bf2f(unsigned short s) {
    union { unsigned u; float f; } v; v.u = ((unsigned)s) << 16;
    return v.f;
}

// Lb layout: (c,h,d,n) -> ((c*H+h)*D + d)*N + n   [bf16]
// Lane d owns all 16 n's contiguously -> b128 stores/loads in K1/K3,
// u32-packed n-pairs in K2.

// ---------------------------------------------------------------------------
// K1: 4-wave blocks, one head x 4 consecutive chunks. Wave w scans chunk
// cq*4+w from zero. Contiguous float4/thread B-panel staging (dt-scaled);
// A-table stored [h][T] for K3. Writes L (bf16, [c][h][d][n]), P[h][c], A.
// ---------------------------------------------------------------------------
__global__ __launch_bounds__(256)
void k1_local(const float* __restrict__ x, const float* __restrict__ dt,
              const float* __restrict__ B, const float* __restrict__ mask,
              const float* __restrict__ log_decay,
              unsigned short* __restrict__ Lb, float* __restrict__ Pbuf,
              float* __restrict__ Abuf) {
    const int cq = blockIdx.x, h = blockIdx.y;
    const int tid = threadIdx.x;
    const int w = tid >> 6, d = tid & 63;
    const int c = cq * CPB + w;
    const int t00 = cq * CPB * CL;                 // 64 t-rows per block
    const float rate = -__expf(log_decay[h]);

    __shared__ float Bs[CPB * CL * N];             // 4 KB, dt-scaled
    __shared__ float As[CPB * CL];                 // 256 B
    {
        const float4* Bg = (const float4*)B;
        const int j = tid;                         // exactly 256 float4s
        const int row = j >> 2, off = j & 3;
        const int t = t00 + row;
        const float dtv = dt[t * H + h];
        float4 bv = Bg[(t * H + h) * (N / 4) + off];
        bv.x *= dtv; bv.y *= dtv; bv.z *= dtv; bv.w *= dtv;
        ((float4*)Bs)[j] = bv;
        if (off == 0) {
            const float av = (1.f - mask[t]) * __expf(dtv * rate);
            As[row] = av;
            Abuf[h * T_LEN + t] = av;              // [h][T]: coalesced in K3
        }
    }
    __syncthreads();

    float s[N];
#pragma unroll
    for (int n = 0; n < N; ++n) s[n] = 0.f;
    float P = 1.f;
    const int t0 = c * CL;

#pragma unroll
    for (int ss = 0; ss < CL; ++ss) {
        const float a  = As[w * CL + ss];          // LDS broadcast
        const float xv = x[((t0 + ss) * H + h) * D + d];
        P *= a;
        const float4* Br4 = (const float4*)(Bs + (w * CL + ss) * N);
#pragma unroll
        for (int q = 0; q < 4; ++q) {              // ds_read_b128 broadcast
            const float4 bv = Br4[q];
            s[4*q+0] = a * s[4*q+0] + bv.x * xv;
            s[4*q+1] = a * s[4*q+1] + bv.y * xv;
            s[4*q+2] = a * s[4*q+2] + bv.z * xv;
            s[4*q+3] = a * s[4*q+3] + bv.w * xv;
        }
    }

    // pack 16 bf16 -> 2x uint4 (b128 stores, wave writes 2KB contiguous)
    unsigned pk[8];
#pragma unroll
    for (int i = 0; i < 8; ++i)
        pk[i] = (unsigned)f2bf(s[2*i]) | ((unsigned)f2bf(s[2*i+1]) << 16);
    uint4* Lp = (uint4*)(Lb + ((size_t)((c * H + h) * D + d)) * N);
    Lp[0] = make_uint4(pk[0], pk[1], pk[2], pk[3]);
    Lp[1] = make_uint4(pk[4], pk[5], pk[6], pk[7]);
    if (d == 0) Pbuf[h * NC + c] = P;              // [h][c]
}

// ---------------------------------------------------------------------------
// K2: 128 blocks x 64 threads; each thread owns an adjacent n-pair of one
// (h,d) column -> all Lb traffic is u32-packed (half the load/store count).
// h = bi>>3 block-uniform -> P reads are s_loads (same P for both pair
// elements). 2 rounds of 128-deep prefetch. Overwrites L in place with
// chunk ENTRY states; writes next_carry (f32, [h][n][d]).
// ---------------------------------------------------------------------------
__global__ __launch_bounds__(64)
void k2_combine(const float* __restrict__ initial_carry,
                unsigned short* __restrict__ LE, const float* __restrict__ Pbuf,
                float* __restrict__ next_carry) {
    const int idx2 = blockIdx.x * 64 + threadIdx.x;  // u32 index, 0..8191
    const int iN = idx2 * 2;                         // h*1024 + d*16 + n0
    const int n0 = iN & 15, d = (iN >> 4) & 63;
    const int h = blockIdx.x >> 3;                   // block-uniform
    unsigned* LEu = (unsigned*)LE;

    float c0 = initial_carry[h * 1024 + n0 * 64 + d];
    float c1 = initial_carry[h * 1024 + (n0 + 1) * 64 + d];

#pragma unroll 1
    for (int r = 0; r < NC / 128; ++r) {             // 2 rounds
        unsigned l[128];
#pragma unroll
        for (int k = 0; k < 128; ++k)
            l[k] = LEu[(size_t)(r * 128 + k) * (HND / 2) + idx2];
#pragma unroll
        for (int k = 0; k < 128; ++k) {
            const float p = Pbuf[h * NC + r * 128 + k];          // s_load
            LEu[(size_t)(r * 128 + k) * (HND / 2) + idx2] =
                (unsigned)f2bf(c0) | ((unsigned)f2bf(c1) << 16); // entry
            c0 = p * c0 + bf2f((unsigned short)(l[k] & 0xffffu));
            c1 = p * c1 + bf2f((unsigned short)(l[k] >> 16));
        }
    }
    next_carry[h * 1024 + n0 * 64 + d] = c0;
    next_carry[h * 1024 + (n0 + 1) * 64 + d] = c1;
}

// ---------------------------------------------------------------------------
// K3: 4-wave blocks mirroring K1. Wave w re-scans chunk cq*4+w from its
// bf16 entry state (2x b128 loads) with fused C-projection + skip. A from
// table. Nontemporal output stores.
// ---------------------------------------------------------------------------
__global__ __launch_bounds__(256)
void k3_scan(const float* __restrict__ x, const float* __restrict__ dt,
             const float* __restrict__ B, const float* __restrict__ C,
             const float* __restrict__ skip_weight,
             const float* __restrict__ Abuf,
             const unsigned short* __restrict__ Eb, float* __restrict__ out) {
    const int cq = blockIdx.x, h = blockIdx.y;
    const int tid = threadIdx.x;
    const int w = tid >> 6, d = tid & 63;
    const int c = cq * CPB + w;
    const int t00 = cq * CPB * CL;

    __shared__ float Bs[CPB * CL * N], Cs[CPB * CL * N];  // 8 KB
    __shared__ float As[CPB * CL];
    {
        const float4* Bg = (const float4*)B;
        const float4* Cg = (const float4*)C;
        const int j = tid;
        const int row = j >> 2, off = j & 3;
        const int t = t00 + row;
        const float dtv = dt[t * H + h];
        float4 bv = Bg[(t * H + h) * (N / 4) + off];
        bv.x *= dtv; bv.y *= dtv; bv.z *= dtv; bv.w *= dtv;
        ((float4*)Bs)[j] = bv;
        ((float4*)Cs)[j] = Cg[(t * H + h) * (N / 4) + off];
        if (tid < CPB * CL) As[tid] = Abuf[h * T_LEN + t00 + tid]; // coalesced
    }
    __syncthreads();

    float s[N];
    {
        const uint4* Ep = (const uint4*)(Eb + ((size_t)((c * H + h) * D + d)) * N);
        const uint4 e0 = Ep[0], e1 = Ep[1];
        const unsigned ew[8] = {e0.x, e0.y, e0.z, e0.w, e1.x, e1.y, e1.z, e1.w};
#pragma unroll
        for (int i = 0; i < 8; ++i) {
            s[2*i]   = bf2f((unsigned short)(ew[i] & 0xffffu));
            s[2*i+1] = bf2f((unsigned short)(ew[i] >> 16));
        }
    }

    const float swv = skip_weight[h * D + d];
    const int t0 = c * CL;
#pragma unroll
    for (int ss = 0; ss < CL; ++ss) {
        const int t = t0 + ss;
        const float a  = As[w * CL + ss];
        const float xv = x[(t * H + h) * D + d];
        float acc = swv * xv;
        const float4* Br4 = (const float4*)(Bs + (w * CL + ss) * N);
        const float4* Cr4 = (const float4*)(Cs + (w * CL + ss) * N);
#pragma unroll
        for (int q = 0; q < 4; ++q) {
            const float4 bv = Br4[q];
            const float4 cv = Cr4[q];
            s[4*q+0] = a * s[4*q+0] + bv.x * xv;  acc += cv.x * s[4*q+0];
            s[4*q+1] = a * s[4*q+1] + bv.y * xv;  acc += cv.y * s[4*q+1];
            s[4*q+2] = a * s[4*q+2] + bv.z * xv;  acc += cv.z * s[4*q+2];
            s[4*q+3] = a * s[4*q+3] + bv.w * xv;  acc += cv.w * s[4*q+3];
        }
        __builtin_nontemporal_store(acc, &out[(t * H + h) * D + d]);
    }
}

extern "C" void kernel_launch(void* const* d_in, const int* in_sizes, int n_in,
                              void* d_out, int out_size, void* d_ws, size_t ws_size,
                              hipStream_t stream) {
    const float* x    = (const float*)d_in[0];
    const float* dt   = (const float*)d_in[1];
    const float* B    = (const float*)d_in[2];
    const float* C    = (const float*)d_in[3];
    const float* mask = (const float*)d_in[4];
    const float* ic   = (const float*)d_in[5];
    const float* ld   = (const float*)d_in[6];
    const float* sw   = (const float*)d_in[7];
    float* out = (float*)d_out;

    // ws: [Pbuf 16KB][Abuf 256KB @ +16KB][Lb bf16 8.4MB @ +272KB]
    float* Pbuf = (float*)d_ws;
    float* Abuf = (float*)((char*)d_ws + 16384);
    unsigned short* Lb = (unsigned short*)((char*)d_ws + 16384 + T_LEN * H * 4);

    dim3 grid(NC / CPB, H), block(256);
    k1_local<<<grid, block, 0, stream>>>(x, dt, B, mask, ld, Lb, Pbuf, Abuf);
    k2_combine<<<dim3(HND / 128), dim3(64), 0, stream>>>(ic, Lb, Pbuf, out);
    k3_scan<<<grid, block, 0, stream>>>(x, dt, B, C, sw, Abuf, Lb, out + HND);
}

// Round 20
// 34.502 us; speedup vs baseline: 1.2017x; 1.2017x over previous
//
#include <hip/hip_runtime.h>

#define T_LEN 4096
#define H 16
#define N 16
#define D 64
#define NC 256
#define CL (T_LEN / NC)   // 16
#define CPB 4             // chunks (waves) per block -> 256-thread blocks
#define HND (H * N * D)   // 16384

static __device__ __forceinline__ unsigned short f2bf(float f) {
    union { float f; unsigned u; } v; v.f = f;
    unsigned r = (v.u + 0x7fffu + ((v.u >> 16) & 1u)) >> 16;
    return (unsigned short)r;
}
static __device__ __forceinline__ float bf2f(unsigned short s) {
    union { unsigned u; float f; } v; v.u = ((unsigned)s) << 16;
    return v.f;
}

// ---------------------------------------------------------------------------
// K1 (r18 proven): 4-wave blocks, one head x 4 consecutive chunks. Wave w
// scans chunk cq*4+w from zero. Contiguous float4/thread B-panel staging
// (dt-scaled); A-table stored [h][T] for K3.
// Writes L[c][h][n][d] (bf16), P[h][c] (f32), A (f32).
// ---------------------------------------------------------------------------
__global__ __launch_bounds__(256)
void k1_local(const float* __restrict__ x, const float* __restrict__ dt,
              const float* __restrict__ B, const float* __restrict__ mask,
              const float* __restrict__ log_decay,
              unsigned short* __restrict__ Lb, float* __restrict__ Pbuf,
              float* __restrict__ Abuf) {
    const int cq = blockIdx.x, h = blockIdx.y;
    const int tid = threadIdx.x;
    const int w = tid >> 6, d = tid & 63;
    const int c = cq * CPB + w;
    const int t00 = cq * CPB * CL;                 // 64 t-rows per block
    const float rate = -__expf(log_decay[h]);

    __shared__ float Bs[CPB * CL * N];             // 4 KB, dt-scaled
    __shared__ float As[CPB * CL];                 // 256 B
    {
        const float4* Bg = (const float4*)B;
        const int j = tid;                         // exactly 256 float4s
        const int row = j >> 2, off = j & 3;
        const int t = t00 + row;
        const float dtv = dt[t * H + h];
        float4 bv = Bg[(t * H + h) * (N / 4) + off];
        bv.x *= dtv; bv.y *= dtv; bv.z *= dtv; bv.w *= dtv;
        ((float4*)Bs)[j] = bv;
        if (off == 0) {
            const float av = (1.f - mask[t]) * __expf(dtv * rate);
            As[row] = av;
            Abuf[h * T_LEN + t] = av;              // [h][T]: coalesced in K3
        }
    }
    __syncthreads();

    float s[N];
#pragma unroll
    for (int n = 0; n < N; ++n) s[n] = 0.f;
    float P = 1.f;
    const int t0 = c * CL;

#pragma unroll
    for (int ss = 0; ss < CL; ++ss) {
        const float a  = As[w * CL + ss];          // LDS broadcast
        const float xv = x[((t0 + ss) * H + h) * D + d];
        P *= a;
        const float4* Br4 = (const float4*)(Bs + (w * CL + ss) * N);
#pragma unroll
        for (int q = 0; q < 4; ++q) {              // ds_read_b128 broadcast
            const float4 bv = Br4[q];
            s[4*q+0] = a * s[4*q+0] + bv.x * xv;
            s[4*q+1] = a * s[4*q+1] + bv.y * xv;
            s[4*q+2] = a * s[4*q+2] + bv.z * xv;
            s[4*q+3] = a * s[4*q+3] + bv.w * xv;
        }
    }

    unsigned short* Lp = Lb + ((size_t)(c * H + h) * N) * D + d;
#pragma unroll
    for (int n = 0; n < N; ++n) Lp[n * D] = f2bf(s[n]);
    if (d == 0) Pbuf[h * NC + c] = P;              // [h][c]
}

// ---------------------------------------------------------------------------
// K2 (r18 proven): 256 blocks x 64 threads (1 block/CU chip-wide spread).
// h = bi>>4 block-uniform -> P reads are s_loads. 2 rounds of 128-deep
// prefetch. Overwrites L in place with chunk ENTRY states (bf16);
// writes next_carry (f32).
// ---------------------------------------------------------------------------
__global__ __launch_bounds__(64)
void k2_combine(const float* __restrict__ initial_carry,
                unsigned short* __restrict__ LE, const float* __restrict__ Pbuf,
                float* __restrict__ next_carry) {
    const int idx = blockIdx.x * 64 + threadIdx.x;   // h*1024 + n*64 + d
    const int h = blockIdx.x >> 4;                   // block-uniform
    float carry = initial_carry[idx];

#pragma unroll 1
    for (int r = 0; r < NC / 128; ++r) {             // 2 rounds
        float l[128];
#pragma unroll
        for (int k = 0; k < 128; ++k)
            l[k] = bf2f(LE[(size_t)(r * 128 + k) * HND + idx]);
#pragma unroll
        for (int k = 0; k < 128; ++k) {
            const float p = Pbuf[h * NC + r * 128 + k];          // s_load
            LE[(size_t)(r * 128 + k) * HND + idx] = f2bf(carry); // entry
            carry = p * carry + l[k];
        }
    }
    next_carry[idx] = carry;
}

// ---------------------------------------------------------------------------
// K3 (r18 proven): 4-wave blocks mirroring K1. Wave w re-scans chunk cq*4+w
// from its bf16 entry state with fused C-projection + skip. A from table.
// Nontemporal output stores.
// ---------------------------------------------------------------------------
__global__ __launch_bounds__(256)
void k3_scan(const float* __restrict__ x, const float* __restrict__ dt,
             const float* __restrict__ B, const float* __restrict__ C,
             const float* __restrict__ skip_weight,
             const float* __restrict__ Abuf,
             const unsigned short* __restrict__ Eb, float* __restrict__ out) {
    const int cq = blockIdx.x, h = blockIdx.y;
    const int tid = threadIdx.x;
    const int w = tid >> 6, d = tid & 63;
    const int c = cq * CPB + w;
    const int t00 = cq * CPB * CL;

    __shared__ float Bs[CPB * CL * N], Cs[CPB * CL * N];  // 8 KB
    __shared__ float As[CPB * CL];
    {
        const float4* Bg = (const float4*)B;
        const float4* Cg = (const float4*)C;
        const int j = tid;
        const int row = j >> 2, off = j & 3;
        const int t = t00 + row;
        const float dtv = dt[t * H + h];
        float4 bv = Bg[(t * H + h) * (N / 4) + off];
        bv.x *= dtv; bv.y *= dtv; bv.z *= dtv; bv.w *= dtv;
        ((float4*)Bs)[j] = bv;
        ((float4*)Cs)[j] = Cg[(t * H + h) * (N / 4) + off];
        if (tid < CPB * CL) As[tid] = Abuf[h * T_LEN + t00 + tid]; // coalesced
    }
    __syncthreads();

    float s[N];
    const unsigned short* Ep = Eb + ((size_t)(c * H + h) * N) * D + d;
#pragma unroll
    for (int n = 0; n < N; ++n) s[n] = bf2f(Ep[n * D]);

    const float swv = skip_weight[h * D + d];
    const int t0 = c * CL;
#pragma unroll
    for (int ss = 0; ss < CL; ++ss) {
        const int t = t0 + ss;
        const float a  = As[w * CL + ss];
        const float xv = x[(t * H + h) * D + d];
        float acc = swv * xv;
        const float4* Br4 = (const float4*)(Bs + (w * CL + ss) * N);
        const float4* Cr4 = (const float4*)(Cs + (w * CL + ss) * N);
#pragma unroll
        for (int q = 0; q < 4; ++q) {
            const float4 bv = Br4[q];
            const float4 cv = Cr4[q];
            s[4*q+0] = a * s[4*q+0] + bv.x * xv;  acc += cv.x * s[4*q+0];
            s[4*q+1] = a * s[4*q+1] + bv.y * xv;  acc += cv.y * s[4*q+1];
            s[4*q+2] = a * s[4*q+2] + bv.z * xv;  acc += cv.z * s[4*q+2];
            s[4*q+3] = a * s[4*q+3] + bv.w * xv;  acc += cv.w * s[4*q+3];
        }
        __builtin_nontemporal_store(acc, &out[(t * H + h) * D + d]);
    }
}

extern "C" void kernel_launch(void* const* d_in, const int* in_sizes, int n_in,
                              void* d_out, int out_size, void* d_ws, size_t ws_size,
                              hipStream_t stream) {
    const float* x    = (const float*)d_in[0];
    const float* dt   = (const float*)d_in[1];
    const float* B    = (const float*)d_in[2];
    const float* C    = (const float*)d_in[3];
    const float* mask = (const float*)d_in[4];
    const float* ic   = (const float*)d_in[5];
    const float* ld   = (const float*)d_in[6];
    const float* sw   = (const float*)d_in[7];
    float* out = (float*)d_out;

    // ws: [Pbuf 16KB][Abuf 256KB @ +16KB][Lb bf16 8.4MB @ +272KB]
    float* Pbuf = (float*)d_ws;
    float* Abuf = (float*)((char*)d_ws + 16384);
    unsigned short* Lb = (unsigned short*)((char*)d_ws + 16384 + T_LEN * H * 4);

    dim3 grid(NC / CPB, H), block(256);
    k1_local<<<grid, block, 0, stream>>>(x, dt, B, mask, ld, Lb, Pbuf, Abuf);
    k2_combine<<<dim3(HND / 64), dim3(64), 0, stream>>>(ic, Lb, Pbuf, out);
    k3_scan<<<grid, block, 0, stream>>>(x, dt, B, C, sw, Abuf, Lb, out + HND);
}